// Round 3
// baseline (368.254 us; speedup 1.0000x reference)
//
#include <hip/hip_runtime.h>

#define LO 506      // L_out
#define LL 512      // L
#define CC 128      // C
#define FF 128      // F
#define KC 896      // K*C (reduction dim)
#define BK 64       // K-tile
#define NK 14       // 896/64
#define XS 72       // Xs row stride in bf16 elems (64 + 8 pad, 144 B: 16B-aligned, breaks pow2 bank stride)

typedef __attribute__((ext_vector_type(8))) short short8;     // 8 bf16 = 4 VGPR (MFMA operand)
typedef __attribute__((ext_vector_type(4))) float floatx4;    // MFMA acc / float4 load
typedef __attribute__((ext_vector_type(4))) unsigned int uintx4;
typedef unsigned short ushort_t;

static __device__ __forceinline__ ushort_t f2bf(float f) {    // RNE f32 -> bf16
    union { float f; unsigned int u; } c; c.f = f;
    unsigned int u = c.u;
    return (ushort_t)((u + 0x7fffu + ((u >> 16) & 1u)) >> 16);
}
static __device__ __forceinline__ unsigned int pk2(float a, float b) {
    return (unsigned int)f2bf(a) | ((unsigned int)f2bf(b) << 16);
}

__global__ __launch_bounds__(256, 2)
void local_block_kernel(const float* __restrict__ x,
                        const float* __restrict__ wg,
                        const float* __restrict__ bias,
                        const float* __restrict__ gamma,
                        const float* __restrict__ beta,
                        const float* __restrict__ mmean,
                        const float* __restrict__ mvar,
                        float* __restrict__ out)
{
    const int l    = blockIdx.x;          // output position, owns W[l] (896x128 fp32)
    const int t    = threadIdx.x;         // 256 threads = 4 waves
    const int lane = t & 63;
    const int wave = t >> 6;
    const int q    = lane >> 4;           // quad within wave
    const int l16  = lane & 15;
    const int wr   = wave >> 1;           // wave row (batch 64-half)
    const int wc   = wave & 1;            // wave col (f 64-half)

    __shared__ __align__(16) ushort_t Xs[128 * XS];   // [b][k] bf16, k-contig
    __shared__ __align__(16) ushort_t Wt[128 * 64];   // [f][k] bf16, k-contig, 16B-unit XOR swizzle

    // ---- A staging map: thread -> (row m = t>>1, k-half = (t&1)*32); 32 floats = 8 x float4
    const int am  = t >> 1;
    const int ak0 = (t & 1) * 32;
    const float* aptr = x + am * (LL * CC) + l * CC + ak0;    // patch row is contiguous in x
    ushort_t* asd = &Xs[am * XS + ak0];

    // ---- W staging map: thread -> (f = t&127, k-half = (t>>7)*32); 32 strided dword loads
    const int wf  = t & 127;
    const int wkh = (t >> 7) * 32;
    const float* wptr = wg + (size_t)l * (KC * FF) + wf;

    floatx4 acc[4][4] = {};               // 64 fp32 accumulators

    floatx4 areg[8];
    float   wreg[32];

#define LOAD_A(KT) { const float* p = aptr + (KT) * BK;                         \
        _Pragma("unroll") for (int v = 0; v < 8; ++v)                           \
            areg[v] = *(const floatx4*)(p + v * 4); }

#define LOAD_W(KT) { const float* p = wptr + (size_t)((KT) * BK + wkh) * FF;    \
        _Pragma("unroll") for (int j = 0; j < 32; ++j)                          \
            wreg[j] = p[j * FF]; }

    LOAD_A(0); LOAD_W(0);

    for (int kt = 0; kt < NK; ++kt) {
        __syncthreads();                  // previous tile's LDS reads done
        // ---- stage A: convert 32 f32 -> 32 bf16, 4 x ds_write_b128
#pragma unroll
        for (int v = 0; v < 4; ++v) {
            uintx4 av = { pk2(areg[2*v].x,   areg[2*v].y),
                          pk2(areg[2*v].z,   areg[2*v].w),
                          pk2(areg[2*v+1].x, areg[2*v+1].y),
                          pk2(areg[2*v+1].z, areg[2*v+1].w) };
            *(uintx4*)(asd + v * 8) = av;
        }
        // ---- stage W transposed: 8 k-contig bf16 per f per b128, XOR swizzle on 16B units
#pragma unroll
        for (int rr = 0; rr < 4; ++rr) {
            uintx4 wv = { pk2(wreg[rr*8+0], wreg[rr*8+1]),
                          pk2(wreg[rr*8+2], wreg[rr*8+3]),
                          pk2(wreg[rr*8+4], wreg[rr*8+5]),
                          pk2(wreg[rr*8+6], wreg[rr*8+7]) };
            int unit = ((wkh >> 3) + rr) ^ (wf & 7);          // k-unit XOR f
            *(uintx4*)&Wt[wf * 64 + unit * 8] = wv;
        }
        __syncthreads();
        if (kt + 1 < NK) { LOAD_A(kt + 1); LOAD_W(kt + 1); }  // prefetch overlaps MFMA
        // ---- compute: 2 x 16 MFMAs (K=32 each)
#pragma unroll
        for (int r = 0; r < 2; ++r) {
            short8 af[4], bfr[4];
#pragma unroll
            for (int mi = 0; mi < 4; ++mi)
                af[mi] = *(const short8*)&Xs[(wr*64 + mi*16 + l16) * XS + r*32 + q*8];
#pragma unroll
            for (int ni = 0; ni < 4; ++ni) {
                int f = wc*64 + ni*16 + l16;
                int unit = (r*4 + q) ^ (f & 7);
                bfr[ni] = *(const short8*)&Wt[f * 64 + unit * 8];
            }
#pragma unroll
            for (int mi = 0; mi < 4; ++mi)
#pragma unroll
                for (int ni = 0; ni < 4; ++ni)
                    acc[mi][ni] = __builtin_amdgcn_mfma_f32_16x16x32_bf16(
                        af[mi], bfr[ni], acc[mi][ni], 0, 0, 0);
        }
    }

    // ---- epilogue: fold bias + BN into per-f scale/offset, relu, store fp32
#pragma unroll
    for (int ni = 0; ni < 4; ++ni) {
        int f = wc*64 + ni*16 + l16;
        float inv = gamma[f] * rsqrtf(mvar[f] + 1e-3f);
        float off = bias[l * FF + f] * inv + beta[f] - mmean[f] * inv;
#pragma unroll
        for (int mi = 0; mi < 4; ++mi) {
#pragma unroll
            for (int rg = 0; rg < 4; ++rg) {
                int b = wr*64 + mi*16 + q*4 + rg;              // C/D: row=(lane>>4)*4+reg
                float v = acc[mi][ni][rg] * inv + off;
                out[((size_t)b * LO + l) * FF + f] = fmaxf(v, 0.0f);
            }
        }
    }
#undef LOAD_A
#undef LOAD_W
}

extern "C" void kernel_launch(void* const* d_in, const int* in_sizes, int n_in,
                              void* d_out, int out_size, void* d_ws, size_t ws_size,
                              hipStream_t stream) {
    const float* x     = (const float*)d_in[0];
    const float* w     = (const float*)d_in[1];
    const float* bias  = (const float*)d_in[2];
    const float* gamma = (const float*)d_in[3];
    const float* beta  = (const float*)d_in[4];
    const float* mmean = (const float*)d_in[5];
    const float* mvar  = (const float*)d_in[6];
    float* out = (float*)d_out;

    local_block_kernel<<<dim3(LO), dim3(256), 0, stream>>>(
        x, w, bias, gamma, beta, mmean, mvar, out);
}

// Round 4
// 368.065 us; speedup vs baseline: 1.0005x; 1.0005x over previous
//
#include <hip/hip_runtime.h>

#define LO 506      // L_out
#define LL 512      // L
#define CC 128      // C
#define FF 128      // F
#define KC 896      // K*C (reduction dim)
#define BK 64       // K-tile
#define NK 14       // 896/64
#define XS 72       // Xs row stride in bf16 elems (64 + 8 pad; 144 B row: 16B-aligned, phase-balanced banks)

typedef __attribute__((ext_vector_type(8))) short short8;     // 8 bf16 = 4 VGPR (MFMA operand)
typedef __attribute__((ext_vector_type(4))) float floatx4;    // MFMA acc / float4 load
typedef __attribute__((ext_vector_type(4))) unsigned int uintx4;
typedef unsigned short ushort_t;

static __device__ __forceinline__ ushort_t f2bf(float f) {    // RNE f32 -> bf16
    union { float f; unsigned int u; } c; c.f = f;
    unsigned int u = c.u;
    return (ushort_t)((u + 0x7fffu + ((u >> 16) & 1u)) >> 16);
}
static __device__ __forceinline__ unsigned int pk2(float a, float b) {
    return (unsigned int)f2bf(a) | ((unsigned int)f2bf(b) << 16);
}

// grid = 1012: blockIdx.x = l*2 + bhalf. 64-batch x 128-f tile per block.
// All 1012 blocks co-resident at 4 blocks/CU -> sibling blocks share W tile via L2/L3.
__global__ __launch_bounds__(256, 4)
void local_block_kernel(const float* __restrict__ x,
                        const float* __restrict__ wg,
                        const float* __restrict__ bias,
                        const float* __restrict__ gamma,
                        const float* __restrict__ beta,
                        const float* __restrict__ mmean,
                        const float* __restrict__ mvar,
                        float* __restrict__ out)
{
    const int bid   = blockIdx.x;
    const int l     = bid >> 1;           // output position, owns W[l] (896x128 fp32)
    const int bhalf = bid & 1;            // which 64-batch half
    const int t    = threadIdx.x;         // 256 threads = 4 waves
    const int lane = t & 63;
    const int wave = t >> 6;
    const int q    = lane >> 4;           // quad within wave
    const int l16  = lane & 15;
    const int wr   = wave >> 1;           // wave row (batch 32-half of the 64)
    const int wc   = wave & 1;            // wave col (f 64-half)

    __shared__ __align__(16) ushort_t Xs[64 * XS];    // [b][k] bf16, k-contig (9.2 KB)
    __shared__ __align__(16) ushort_t Wt[128 * 64];   // [f][k] bf16, k-contig, 16B-unit XOR swizzle (16 KB)

    // ---- A staging map: thread -> (row am = t>>2, k-quarter = (t&3)*16); 16 floats = 4 x float4
    const int am  = t >> 2;
    const int ak0 = (t & 3) * 16;
    const float* aptr = x + (size_t)(bhalf * 64 + am) * (LL * CC) + l * CC + ak0;
    ushort_t* asd = &Xs[am * XS + ak0];

    // ---- W staging map: thread -> (f = t&127, k-half = (t>>7)*32); 32 strided dword loads
    const int wf  = t & 127;
    const int wkh = (t >> 7) * 32;
    const float* wptr = wg + (size_t)l * (KC * FF) + wf;

    floatx4 acc[2][4] = {};               // 32 fp32 accumulators (2 m-tiles x 4 n-tiles)

    floatx4 areg[4];
    float   wreg[32];

#define LOAD_A(KT) { const float* p = aptr + (KT) * BK;                         \
        _Pragma("unroll") for (int v = 0; v < 4; ++v)                           \
            areg[v] = *(const floatx4*)(p + v * 4); }

#define LOAD_W(KT) { const float* p = wptr + (size_t)((KT) * BK + wkh) * FF;    \
        _Pragma("unroll") for (int j = 0; j < 32; ++j)                          \
            wreg[j] = p[j * FF]; }

    LOAD_A(0); LOAD_W(0);

    for (int kt = 0; kt < NK; ++kt) {
        __syncthreads();                  // previous tile's LDS reads done
        // ---- stage A: convert 16 f32 -> 16 bf16, 2 x ds_write_b128
#pragma unroll
        for (int v = 0; v < 2; ++v) {
            uintx4 av = { pk2(areg[2*v].x,   areg[2*v].y),
                          pk2(areg[2*v].z,   areg[2*v].w),
                          pk2(areg[2*v+1].x, areg[2*v+1].y),
                          pk2(areg[2*v+1].z, areg[2*v+1].w) };
            *(uintx4*)(asd + v * 8) = av;
        }
        // ---- stage W transposed: 8 k-contig bf16 per f per b128, XOR swizzle on 16B units
#pragma unroll
        for (int rr = 0; rr < 4; ++rr) {
            uintx4 wv = { pk2(wreg[rr*8+0], wreg[rr*8+1]),
                          pk2(wreg[rr*8+2], wreg[rr*8+3]),
                          pk2(wreg[rr*8+4], wreg[rr*8+5]),
                          pk2(wreg[rr*8+6], wreg[rr*8+7]) };
            int unit = ((wkh >> 3) + rr) ^ (wf & 7);          // k-unit XOR f
            *(uintx4*)&Wt[wf * 64 + unit * 8] = wv;
        }
        __syncthreads();
        if (kt + 1 < NK) { LOAD_A(kt + 1); LOAD_W(kt + 1); }  // register prefetch overlaps MFMA
        // ---- compute: 2 x 8 MFMAs (K=32 each)
#pragma unroll
        for (int r = 0; r < 2; ++r) {
            short8 af[2], bfr[4];
#pragma unroll
            for (int mi = 0; mi < 2; ++mi)
                af[mi] = *(const short8*)&Xs[(wr*32 + mi*16 + l16) * XS + r*32 + q*8];
#pragma unroll
            for (int ni = 0; ni < 4; ++ni) {
                int f = wc*64 + ni*16 + l16;
                int unit = (r*4 + q) ^ (f & 7);
                bfr[ni] = *(const short8*)&Wt[f * 64 + unit * 8];
            }
#pragma unroll
            for (int mi = 0; mi < 2; ++mi)
#pragma unroll
                for (int ni = 0; ni < 4; ++ni)
                    acc[mi][ni] = __builtin_amdgcn_mfma_f32_16x16x32_bf16(
                        af[mi], bfr[ni], acc[mi][ni], 0, 0, 0);
        }
    }

    // ---- epilogue: fold bias + BN into per-f scale/offset, relu, store fp32
#pragma unroll
    for (int ni = 0; ni < 4; ++ni) {
        int f = wc*64 + ni*16 + l16;
        float inv = gamma[f] * rsqrtf(mvar[f] + 1e-3f);
        float off = bias[l * FF + f] * inv + beta[f] - mmean[f] * inv;
#pragma unroll
        for (int mi = 0; mi < 2; ++mi) {
#pragma unroll
            for (int rg = 0; rg < 4; ++rg) {
                int b = bhalf*64 + wr*32 + mi*16 + q*4 + rg;   // C/D: row=(lane>>4)*4+reg
                float v = acc[mi][ni][rg] * inv + off;
                out[((size_t)b * LO + l) * FF + f] = fmaxf(v, 0.0f);
            }
        }
    }
#undef LOAD_A
#undef LOAD_W
}

extern "C" void kernel_launch(void* const* d_in, const int* in_sizes, int n_in,
                              void* d_out, int out_size, void* d_ws, size_t ws_size,
                              hipStream_t stream) {
    const float* x     = (const float*)d_in[0];
    const float* w     = (const float*)d_in[1];
    const float* bias  = (const float*)d_in[2];
    const float* gamma = (const float*)d_in[3];
    const float* beta  = (const float*)d_in[4];
    const float* mmean = (const float*)d_in[5];
    const float* mvar  = (const float*)d_in[6];
    float* out = (float*)d_out;

    local_block_kernel<<<dim3(LO * 2), dim3(256), 0, stream>>>(
        x, w, bias, gamma, beta, mmean, mvar, out);
}